// Round 16
// baseline (43.371 us; speedup 1.0000x reference)
//
#include <hip/hip_runtime.h>

// NW kernel regression, double-MFMA (attention structure), r16 tuning:
//   MFMA1: fidx = ssL*(|q|^2+|k|^2-2q.k)+0.5 as rank-13 f16 hi/lo GEMM
//   VALU:  w = lut16[med3(fidx,0,LUTN)]   (fp16 NN LUT, ds_read_u16)
//   MFMA2: [num|den] = W @ [V|1]  (ch8 = 1.0 denominator column)
// r16 changes vs r15 (structure proven, absmax 4.88e-4):
//  - LUT computed once in nw_prep (fp16, in ws); nw_main block-copies 8.2KB
//    to LDS via uint4 (kills per-block trans evals + per-key f32->f16 cvt)
//  - QPB 128 / TPB 256 -> grid 64x32 = 2048 blocks = 8/CU, ~32 waves/CU
//  - manual next-tile prefetch of ka/vfa/vfb (wrap index)
// Conventions (proven r12/r14/r15):
//   A-frag 32x32x16: A[row=lane&31][slot=(lane>>5)*8+j]
//   B-frag:          B[slot=(lane>>5)*8+j][col=lane&31]
//   D:               col=lane&31, row=(reg&3)+8*(reg>>2)+4*(lane>>5)
//   vfrag key perm(g,j)=(j&3)+8*(j>>2)+4*g (+16 for set b), folded in prep.

typedef _Float16 h8 __attribute__((ext_vector_type(8)));
typedef float f32x16 __attribute__((ext_vector_type(16)));
typedef float f32x4 __attribute__((ext_vector_type(4)));

#define NCH 8
#define TPB 256        // 4 waves
#define QPB 128        // 4 waves x 32 query-rows
#define KSB 256        // keys per split = 8 tiles of 32
#define NTILE (KSB / 32)
#define LUTN 4096
#define LUTPAD 4104    // pad to 16B multiple (4104 halves = 8208B = 513 x 16B)

__device__ __forceinline__ float nw_weight_exact(float cd) {
    float r  = __builtin_amdgcn_fractf(cd);
    float sn = __builtin_amdgcn_sinf(r);
    float cs = __builtin_amdgcn_cosf(r);
    float t  = (1.0f - cd) * (1.0f / 3.0f);
    float wt = fmaf(sn, 0.15915494309189535f, fmaf(cs, t, t + t));
    return fmaxf(wt, 0.0f);
}

__device__ __forceinline__ void split16(float x, _Float16& h, _Float16& l) {
    h = (_Float16)x;
    l = (_Float16)(x - (float)h);
}

// prep: kfrag (A1 slots), vfrag (B2 frags, perm-folded), lutg (fp16 LUT)
__global__ __launch_bounds__(256) void nw_prep(const float* __restrict__ k,
                                               const float* __restrict__ v,
                                               const float* __restrict__ kl,
                                               h8* __restrict__ kfrag,
                                               h8* __restrict__ vfrag,
                                               _Float16* __restrict__ lutg,
                                               int M) {
    const int idx = blockIdx.x * 256 + threadIdx.x;
    const float iL = 1.0f / kl[0];
    const float ssL = iL * iL * (float)LUTN;
    if (idx < LUTPAD) {
        lutg[idx] = (idx <= LUTN)
            ? (_Float16)nw_weight_exact(__builtin_amdgcn_sqrtf((float)idx * (1.0f / (float)LUTN)))
            : (_Float16)0.0f;
    }
    if (idx < M) {
        const float x = k[(size_t)idx * 3 + 0];
        const float y = k[(size_t)idx * 3 + 1];
        const float z = k[(size_t)idx * 3 + 2];
        const float cx = -2.0f * ssL * x, cy = -2.0f * ssL * y, cz = -2.0f * ssL * z;
        const float k2 = ssL * fmaf(x, x, fmaf(y, y, z * z));
        _Float16 cxh, cxl, cyh, cyl, czh, czl, k2h, k2l;
        split16(cx, cxh, cxl); split16(cy, cyh, cyl);
        split16(cz, czh, czl); split16(k2, k2h, k2l);
        h8 lo = {cxh, cxh, cxl, cyh, cyh, cyl, czh, czh};
        h8 hi = {czl, k2h, k2l, (_Float16)1.0f, (_Float16)1.0f,
                 (_Float16)0.0f, (_Float16)0.0f, (_Float16)0.0f};
        kfrag[idx * 2 + 0] = lo;
        kfrag[idx * 2 + 1] = hi;
    }
    const int nv = (M / 32) * 128;   // tiles * 2 sets * 64 lanes
    if (idx < nv) {
        const int t = idx >> 7, r = idx & 127;
        const int set = r >> 6, l = r & 63;
        const int ch = l & 31, g = l >> 5;
        h8 o;
#pragma unroll
        for (int j = 0; j < 8; ++j) {
            const int key = t * 32 + set * 16 + ((j & 3) + 8 * (j >> 2) + 4 * g);
            const float val = (ch < 8) ? v[(size_t)key * 8 + ch]
                                       : (ch == 8 ? 1.0f : 0.0f);
            o[j] = (_Float16)val;
        }
        vfrag[(size_t)(t * 2 + set) * 64 + l] = o;
    }
}

__global__ __launch_bounds__(TPB) void nw_main(const float* __restrict__ q,
                                               const h8* __restrict__ kfrag,
                                               const h8* __restrict__ vfrag,
                                               const _Float16* __restrict__ lutg,
                                               const float* __restrict__ kl,
                                               float* __restrict__ part,
                                               int N) {
    __shared__ uint4 lutbuf[LUTPAD / 8];   // 8208 B
    _Float16* lutw16 = (_Float16*)lutbuf;

    const int tid  = threadIdx.x;
    const int lane = tid & 63;
    const int wid  = tid >> 6;
    const int qg   = blockIdx.x;
    const int sb   = blockIdx.y;

    // stage fp16 LUT global -> LDS (513 x 16B)
    {
        const uint4* g4 = (const uint4*)lutg;
        for (int e = tid; e < LUTPAD / 8; e += TPB) lutbuf[e] = g4[e];
    }
    __syncthreads();

    const float iL = 1.0f / kl[0];
    const float ssL = iL * iL * (float)LUTN;

    const int row = lane & 31;
    const int g   = lane >> 5;
    const int qi  = qg * QPB + wid * 32 + row;
    const float qx = q[qi * 3 + 0];
    const float qy = q[qi * 3 + 1];
    const float qz = q[qi * 3 + 2];
    const float q2 = ssL * fmaf(qx, qx, fmaf(qy, qy, qz * qz)) + 0.5f;

    _Float16 qxh, qxl, qyh, qyl, qzh, qzl, q2h, q2l;
    split16(qx, qxh, qxl); split16(qy, qyh, qyl);
    split16(qz, qzh, qzl); split16(q2, q2h, q2l);
    const _Float16 one = (_Float16)1.0f, zer = (_Float16)0.0f;
    h8 qf;   // B-frag of MFMA1 (constant across tiles)
    qf[0] = g ? qzh : qxh;
    qf[1] = g ? one : qxl;
    qf[2] = g ? one : qxh;
    qf[3] = g ? q2h : qyh;
    qf[4] = g ? q2l : qyl;
    qf[5] = g ? zer : qyh;
    qf[6] = g ? zer : qzh;
    qf[7] = g ? zer : qzl;

    const h8* __restrict__ kfq = kfrag + (size_t)(sb * KSB) * 2;
    const h8* __restrict__ vfq = vfrag + (size_t)(sb * NTILE) * 128;

    f32x16 acc;
#pragma unroll
    for (int e = 0; e < 16; ++e) acc[e] = 0.0f;
    f32x16 zacc;
#pragma unroll
    for (int e = 0; e < 16; ++e) zacc[e] = 0.0f;

    // prefetched tile registers
    h8 ka  = kfq[(size_t)(row) * 2 + g];
    h8 vfa = vfq[lane];
    h8 vfb = vfq[64 + lane];

#pragma unroll 2
    for (int t = 0; t < NTILE; ++t) {
        const int tn = (t + 1) & (NTILE - 1);   // wraps on last iter (harmless)
        const h8 ka_n  = kfq[(size_t)(tn * 32 + row) * 2 + g];
        const h8 vfa_n = vfq[(size_t)(tn * 2 + 0) * 64 + lane];
        const h8 vfb_n = vfq[(size_t)(tn * 2 + 1) * 64 + lane];

        const f32x16 s = __builtin_amdgcn_mfma_f32_32x32x16_f16(ka, qf, zacc, 0, 0, 0);

        h8 afa, afb;
#pragma unroll
        for (int r = 0; r < 8; ++r) {
            const float fx = fmaxf(fminf(s[r], (float)LUTN), 0.0f);      // v_med3
            afa[r] = lutw16[(unsigned)fx];                                // ds_read_u16
        }
#pragma unroll
        for (int r = 0; r < 8; ++r) {
            const float fx = fmaxf(fminf(s[8 + r], (float)LUTN), 0.0f);
            afb[r] = lutw16[(unsigned)fx];
        }
        acc = __builtin_amdgcn_mfma_f32_32x32x16_f16(afa, vfa, acc, 0, 0, 0);
        acc = __builtin_amdgcn_mfma_f32_32x32x16_f16(afb, vfb, acc, 0, 0, 0);

        ka = ka_n; vfa = vfa_n; vfb = vfb_n;
    }

    // D: col=lane&31=channel, row=(reg&3)+8*(reg>>2)+4*g = local query
    const int ch = lane & 31;
    if (ch < 9) {
#pragma unroll
        for (int rq = 0; rq < 4; ++rq) {
            f32x4 o = {acc[4 * rq + 0], acc[4 * rq + 1], acc[4 * rq + 2], acc[4 * rq + 3]};
            const int gi = qg * QPB + wid * 32 + 8 * rq + 4 * g;
            *(f32x4*)(part + ((size_t)sb * 10 + ch) * N + gi) = o;
        }
    }
}

// out[i,c] = (sum_sb num) / (sum_sb den) + 1e-6; coalesced row reads
__global__ __launch_bounds__(256) void nw_reduce(const float* __restrict__ part,
                                                 float* __restrict__ out,
                                                 int N, int nsb) {
    const int i = blockIdx.x * 256 + threadIdx.x;
    if (i >= N) return;
    float o[NCH];
#pragma unroll
    for (int c = 0; c < NCH; ++c) o[c] = 0.0f;
    float den = 0.0f;
    for (int sb = 0; sb < nsb; ++sb) {
        const float* base = part + (size_t)sb * 10 * N + i;
        den += base[8 * (size_t)N];
#pragma unroll
        for (int c = 0; c < NCH; ++c) o[c] += base[(size_t)c * N];
    }
    const float rd = 1.0f / den;
    float4* o4 = (float4*)(out + (size_t)i * NCH);
    o4[0] = make_float4(fmaf(o[0], rd, 1e-6f), fmaf(o[1], rd, 1e-6f),
                        fmaf(o[2], rd, 1e-6f), fmaf(o[3], rd, 1e-6f));
    o4[1] = make_float4(fmaf(o[4], rd, 1e-6f), fmaf(o[5], rd, 1e-6f),
                        fmaf(o[6], rd, 1e-6f), fmaf(o[7], rd, 1e-6f));
}

// generic fallback: one thread per query over all keys (exact math)
__global__ __launch_bounds__(256) void nw_full(const float* __restrict__ q,
                                               const float* __restrict__ k,
                                               const float* __restrict__ v,
                                               const float* __restrict__ kl,
                                               float* __restrict__ out,
                                               int N, int M) {
    const int i = blockIdx.x * 256 + threadIdx.x;
    if (i >= N) return;
    const float qx = q[i * 3 + 0], qy = q[i * 3 + 1], qz = q[i * 3 + 2];
    const float invL = 1.0f / kl[0];
    float num[NCH];
#pragma unroll
    for (int c = 0; c < NCH; ++c) num[c] = 0.0f;
    float den = 0.0f;
    for (int j = 0; j < M; ++j) {
        float dx = qx - k[j * 3 + 0], dy = qy - k[j * 3 + 1], dz = qz - k[j * 3 + 2];
        float d2 = fmaf(dx, dx, fmaf(dy, dy, dz * dz));
        float wt = nw_weight_exact(__builtin_amdgcn_sqrtf(d2) * invL);
        den += wt;
#pragma unroll
        for (int c = 0; c < NCH; ++c) num[c] = fmaf(wt, v[j * NCH + c], num[c]);
    }
    const float rden = 1.0f / den;
#pragma unroll
    for (int c = 0; c < NCH; ++c) out[i * NCH + c] = fmaf(num[c], rden, 1e-6f);
}

extern "C" void kernel_launch(void* const* d_in, const int* in_sizes, int n_in,
                              void* d_out, int out_size, void* d_ws, size_t ws_size,
                              hipStream_t stream) {
    const float* q  = (const float*)d_in[0];
    const float* k  = (const float*)d_in[1];
    const float* v  = (const float*)d_in[2];
    const float* kl = (const float*)d_in[3];
    float* out = (float*)d_out;

    const int N = in_sizes[0] / 3;   // 8192 queries
    const int M = in_sizes[1] / 3;   // 8192 keys

    const int nsb = (M + KSB - 1) / KSB;
    const size_t part_sz  = (size_t)nsb * 10 * N * sizeof(float);
    const size_t kfrag_sz = (size_t)M * 2 * sizeof(h8);
    const size_t vfrag_sz = (size_t)(M / 32) * 128 * sizeof(h8);
    const size_t lut_sz   = (size_t)LUTPAD * sizeof(_Float16);

    if ((N % QPB) == 0 && (M % KSB) == 0 &&
        ws_size >= part_sz + kfrag_sz + vfrag_sz + lut_sz) {
        float*    part  = (float*)d_ws;
        h8*       kfrag = (h8*)((char*)d_ws + part_sz);
        h8*       vfrag = (h8*)((char*)d_ws + part_sz + kfrag_sz);
        _Float16* lutg  = (_Float16*)((char*)d_ws + part_sz + kfrag_sz + vfrag_sz);
        const int nprep = (M / 32) * 128;   // >= M, >= LUTPAD
        nw_prep<<<(nprep + 255) / 256, 256, 0, stream>>>(k, v, kl, kfrag, vfrag, lutg, M);
        dim3 grid(N / QPB, nsb);
        nw_main<<<grid, TPB, 0, stream>>>(q, kfrag, vfrag, lutg, kl, part, N);
        nw_reduce<<<(N + 255) / 256, 256, 0, stream>>>(part, out, N, nsb);
    } else {
        nw_full<<<(N + 255) / 256, 256, 0, stream>>>(q, k, v, kl, out, N, M);
    }
}

// Round 17
// 32.614 us; speedup vs baseline: 1.3298x; 1.3298x over previous
//
#include <hip/hip_runtime.h>

// NW kernel regression, double-MFMA (attention structure) — r15 config verbatim
// (proven 34.1us), with nw_reduce re-gridded: 32 -> 256 blocks (channel dim in
// grid.y), per-thread loads 320 -> 64, coalesced; identical summation order.
//   MFMA1: fidx = ssL*(|q|^2+|k|^2-2q.k)+0.5 as rank-13 f16 hi/lo GEMM
//   VALU:  w = lutw[clamp(fidx)]  (NN 4096-cell f32 LUT, built per block)
//   MFMA2: [num|den] = W @ [V|1]  (ch8 = 1.0 denominator column)
// Conventions (proven r12/r14/r15):
//   A-frag 32x32x16: A[row=lane&31][slot=(lane>>5)*8+j]
//   B-frag:          B[slot=(lane>>5)*8+j][col=lane&31]
//   D:               col=lane&31, row=(reg&3)+8*(reg>>2)+4*(lane>>5)
//   vfrag key perm(g,j)=(j&3)+8*(j>>2)+4*g (+16 for set b), folded in prep.

typedef _Float16 h8 __attribute__((ext_vector_type(8)));
typedef float f32x16 __attribute__((ext_vector_type(16)));
typedef float f32x4 __attribute__((ext_vector_type(4)));

#define NCH 8
#define TPB 512        // 8 waves
#define QPB 256        // 8 waves x 32 query-rows
#define KSB 256        // keys per split = 8 tiles of 32
#define NTILE (KSB / 32)
#define LUTN 4096

__device__ __forceinline__ float nw_weight_exact(float cd) {
    float r  = __builtin_amdgcn_fractf(cd);
    float sn = __builtin_amdgcn_sinf(r);
    float cs = __builtin_amdgcn_cosf(r);
    float t  = (1.0f - cd) * (1.0f / 3.0f);
    float wt = fmaf(sn, 0.15915494309189535f, fmaf(cs, t, t + t));
    return fmaxf(wt, 0.0f);
}

__device__ __forceinline__ void split16(float x, _Float16& h, _Float16& l) {
    h = (_Float16)x;
    l = (_Float16)(x - (float)h);
}

// kfrag[key*2+g][j]: A-side slots; vfrag[(tile*2+set)*64+lane]: B-side V-frags
__global__ __launch_bounds__(256) void nw_prep(const float* __restrict__ k,
                                               const float* __restrict__ v,
                                               const float* __restrict__ kl,
                                               h8* __restrict__ kfrag,
                                               h8* __restrict__ vfrag,
                                               int M) {
    const int idx = blockIdx.x * 256 + threadIdx.x;
    const float iL = 1.0f / kl[0];
    const float ssL = iL * iL * (float)LUTN;
    if (idx < M) {
        const float x = k[(size_t)idx * 3 + 0];
        const float y = k[(size_t)idx * 3 + 1];
        const float z = k[(size_t)idx * 3 + 2];
        const float cx = -2.0f * ssL * x, cy = -2.0f * ssL * y, cz = -2.0f * ssL * z;
        const float k2 = ssL * fmaf(x, x, fmaf(y, y, z * z));
        _Float16 cxh, cxl, cyh, cyl, czh, czl, k2h, k2l;
        split16(cx, cxh, cxl); split16(cy, cyh, cyl);
        split16(cz, czh, czl); split16(k2, k2h, k2l);
        h8 lo = {cxh, cxh, cxl, cyh, cyh, cyl, czh, czh};
        h8 hi = {czl, k2h, k2l, (_Float16)1.0f, (_Float16)1.0f,
                 (_Float16)0.0f, (_Float16)0.0f, (_Float16)0.0f};
        kfrag[idx * 2 + 0] = lo;
        kfrag[idx * 2 + 1] = hi;
    }
    const int nv = (M / 32) * 128;   // tiles * 2 sets * 64 lanes
    if (idx < nv) {
        const int t = idx >> 7, r = idx & 127;
        const int set = r >> 6, l = r & 63;
        const int ch = l & 31, g = l >> 5;
        h8 o;
#pragma unroll
        for (int j = 0; j < 8; ++j) {
            const int key = t * 32 + set * 16 + ((j & 3) + 8 * (j >> 2) + 4 * g);
            const float val = (ch < 8) ? v[(size_t)key * 8 + ch]
                                       : (ch == 8 ? 1.0f : 0.0f);
            o[j] = (_Float16)val;
        }
        vfrag[(size_t)(t * 2 + set) * 64 + l] = o;
    }
}

__global__ __launch_bounds__(TPB) void nw_main(const float* __restrict__ q,
                                               const h8* __restrict__ kfrag,
                                               const h8* __restrict__ vfrag,
                                               const float* __restrict__ kl,
                                               float* __restrict__ part,
                                               int N) {
    __shared__ float lutw[LUTN + 1];

    const int tid  = threadIdx.x;
    const int lane = tid & 63;
    const int wid  = tid >> 6;
    const int qg   = blockIdx.x;
    const int sb   = blockIdx.y;

    const float iL = 1.0f / kl[0];
    const float ssL = iL * iL * (float)LUTN;

    for (int e = tid; e <= LUTN; e += TPB)
        lutw[e] = nw_weight_exact(__builtin_amdgcn_sqrtf((float)e * (1.0f / (float)LUTN)));
    __syncthreads();

    const int row = lane & 31;
    const int g   = lane >> 5;
    const int qi  = qg * QPB + wid * 32 + row;
    const float qx = q[qi * 3 + 0];
    const float qy = q[qi * 3 + 1];
    const float qz = q[qi * 3 + 2];
    const float q2 = ssL * fmaf(qx, qx, fmaf(qy, qy, qz * qz)) + 0.5f;

    _Float16 qxh, qxl, qyh, qyl, qzh, qzl, q2h, q2l;
    split16(qx, qxh, qxl); split16(qy, qyh, qyl);
    split16(qz, qzh, qzl); split16(q2, q2h, q2l);
    const _Float16 one = (_Float16)1.0f, zer = (_Float16)0.0f;
    // B-frag (constant across tiles): g=0 slots0..7, g=1 slots8..15
    h8 qf;
    qf[0] = g ? qzh : qxh;
    qf[1] = g ? one : qxl;
    qf[2] = g ? one : qxh;
    qf[3] = g ? q2h : qyh;
    qf[4] = g ? q2l : qyl;
    qf[5] = g ? zer : qyh;
    qf[6] = g ? zer : qzh;
    qf[7] = g ? zer : qzl;

    const h8* __restrict__ kfq = kfrag + (size_t)(sb * KSB) * 2;
    const h8* __restrict__ vfq = vfrag + (size_t)(sb * NTILE) * 128;

    f32x16 acc;
#pragma unroll
    for (int e = 0; e < 16; ++e) acc[e] = 0.0f;
    f32x16 zacc;
#pragma unroll
    for (int e = 0; e < 16; ++e) zacc[e] = 0.0f;

    for (int t = 0; t < NTILE; ++t) {
        const h8 ka  = kfq[(size_t)(t * 32 + row) * 2 + g];   // A1: per-lane 16B
        const h8 vfa = vfq[(size_t)(t * 2 + 0) * 64 + lane];
        const h8 vfb = vfq[(size_t)(t * 2 + 1) * 64 + lane];

        const f32x16 s = __builtin_amdgcn_mfma_f32_32x32x16_f16(ka, qf, zacc, 0, 0, 0);

        h8 afa, afb;
#pragma unroll
        for (int r = 0; r < 8; ++r) {
            float fx = fmaxf(fminf(s[r], (float)LUTN), 0.0f);
            afa[r] = (_Float16)lutw[(unsigned)fx];
        }
#pragma unroll
        for (int r = 0; r < 8; ++r) {
            float fx = fmaxf(fminf(s[8 + r], (float)LUTN), 0.0f);
            afb[r] = (_Float16)lutw[(unsigned)fx];
        }
        acc = __builtin_amdgcn_mfma_f32_32x32x16_f16(afa, vfa, acc, 0, 0, 0);
        acc = __builtin_amdgcn_mfma_f32_32x32x16_f16(afb, vfb, acc, 0, 0, 0);
    }

    // D: col=lane&31=channel, row=(reg&3)+8*(reg>>2)+4*g = local query
    const int ch = lane & 31;
    if (ch < 9) {
#pragma unroll
        for (int rq = 0; rq < 4; ++rq) {
            f32x4 o = {acc[4 * rq + 0], acc[4 * rq + 1], acc[4 * rq + 2], acc[4 * rq + 3]};
            const int gi = qg * QPB + wid * 32 + 8 * rq + 4 * g;
            *(f32x4*)(part + ((size_t)sb * 10 + ch) * N + gi) = o;
        }
    }
}

// out[i,c] = (sum_sb num) / (sum_sb den) + 1e-6
// grid: x = N/256 query-chunks, y = NCH channels -> 256 blocks (was 32).
// Per-thread: nsb channel loads + nsb den loads, both coalesced; sb order
// ascending (identical to previous reduce -> bitwise-same output).
__global__ __launch_bounds__(256) void nw_reduce(const float* __restrict__ part,
                                                 float* __restrict__ out,
                                                 int N, int nsb) {
    const int i = blockIdx.x * 256 + threadIdx.x;
    const int c = blockIdx.y;
    if (i >= N) return;
    float s = 0.0f, d = 0.0f;
    for (int sb = 0; sb < nsb; ++sb) {
        const float* base = part + (size_t)sb * 10 * N;
        s += base[(size_t)c * N + i];
        d += base[8 * (size_t)N + i];
    }
    out[(size_t)i * NCH + c] = fmaf(s, 1.0f / d, 1e-6f);
}

// generic fallback: one thread per query over all keys (exact math)
__global__ __launch_bounds__(256) void nw_full(const float* __restrict__ q,
                                               const float* __restrict__ k,
                                               const float* __restrict__ v,
                                               const float* __restrict__ kl,
                                               float* __restrict__ out,
                                               int N, int M) {
    const int i = blockIdx.x * 256 + threadIdx.x;
    if (i >= N) return;
    const float qx = q[i * 3 + 0], qy = q[i * 3 + 1], qz = q[i * 3 + 2];
    const float invL = 1.0f / kl[0];
    float num[NCH];
#pragma unroll
    for (int c = 0; c < NCH; ++c) num[c] = 0.0f;
    float den = 0.0f;
    for (int j = 0; j < M; ++j) {
        float dx = qx - k[j * 3 + 0], dy = qy - k[j * 3 + 1], dz = qz - k[j * 3 + 2];
        float d2 = fmaf(dx, dx, fmaf(dy, dy, dz * dz));
        float wt = nw_weight_exact(__builtin_amdgcn_sqrtf(d2) * invL);
        den += wt;
#pragma unroll
        for (int c = 0; c < NCH; ++c) num[c] = fmaf(wt, v[j * NCH + c], num[c]);
    }
    const float rden = 1.0f / den;
#pragma unroll
    for (int c = 0; c < NCH; ++c) out[i * NCH + c] = fmaf(num[c], rden, 1e-6f);
}

extern "C" void kernel_launch(void* const* d_in, const int* in_sizes, int n_in,
                              void* d_out, int out_size, void* d_ws, size_t ws_size,
                              hipStream_t stream) {
    const float* q  = (const float*)d_in[0];
    const float* k  = (const float*)d_in[1];
    const float* v  = (const float*)d_in[2];
    const float* kl = (const float*)d_in[3];
    float* out = (float*)d_out;

    const int N = in_sizes[0] / 3;   // 8192 queries
    const int M = in_sizes[1] / 3;   // 8192 keys

    const int nsb = (M + KSB - 1) / KSB;
    const size_t part_sz  = (size_t)nsb * 10 * N * sizeof(float);
    const size_t kfrag_sz = (size_t)M * 2 * sizeof(h8);
    const size_t vfrag_sz = (size_t)(M / 32) * 128 * sizeof(h8);

    if ((N % QPB) == 0 && (M % KSB) == 0 && ws_size >= part_sz + kfrag_sz + vfrag_sz) {
        float* part  = (float*)d_ws;
        h8*    kfrag = (h8*)((char*)d_ws + part_sz);
        h8*    vfrag = (h8*)((char*)d_ws + part_sz + kfrag_sz);
        const int nprep = (M / 32) * 128;   // >= M
        nw_prep<<<(nprep + 255) / 256, 256, 0, stream>>>(k, v, kl, kfrag, vfrag, M);
        dim3 grid(N / QPB, nsb);
        nw_main<<<grid, TPB, 0, stream>>>(q, kfrag, vfrag, kl, part, N);
        dim3 rgrid((N + 255) / 256, NCH);
        nw_reduce<<<rgrid, 256, 0, stream>>>(part, out, N, nsb);
    } else {
        nw_full<<<(N + 255) / 256, 256, 0, stream>>>(q, k, v, kl, out, N, M);
    }
}

// Round 18
// 32.069 us; speedup vs baseline: 1.3524x; 1.0170x over previous
//
#include <hip/hip_runtime.h>

// NW kernel regression, double-MFMA (attention structure) — r17 skeleton
// (proven 32.6us) with two isolated cuts:
//  (1) KSB 256->512 (nsb 16): halves partial traffic + reduce work; grid
//      32x16=512 blocks = 2/CU = 16 waves/CU (main loop is LDS-throughput
//      bound, not latency bound -> main time should hold).
//  (2) fp16 LUT (isolated from r16's failed bundle): ds_read_u16 lands
//      directly in the A-frag, kills 16 v_cvt/tile, LUT LDS 16.4->8.2KB.
//   MFMA1: fidx = ssL*(|q|^2+|k|^2-2q.k)+0.5 as rank-13 f16 hi/lo GEMM
//   VALU:  w = lut16[med3(fidx,0,LUTN)]
//   MFMA2: [num|den] = W @ [V|1]  (ch8 = 1.0 denominator column)
// Conventions (proven r12/r14/r15/r17):
//   A-frag 32x32x16: A[row=lane&31][slot=(lane>>5)*8+j]
//   B-frag:          B[slot=(lane>>5)*8+j][col=lane&31]
//   D:               col=lane&31, row=(reg&3)+8*(reg>>2)+4*(lane>>5)
//   vfrag key perm(g,j)=(j&3)+8*(j>>2)+4*g (+16 for set b), folded in prep.

typedef _Float16 h8 __attribute__((ext_vector_type(8)));
typedef float f32x16 __attribute__((ext_vector_type(16)));
typedef float f32x4 __attribute__((ext_vector_type(4)));

#define NCH 8
#define TPB 512        // 8 waves
#define QPB 256        // 8 waves x 32 query-rows
#define KSB 512        // keys per split = 16 tiles of 32
#define NTILE (KSB / 32)
#define LUTN 4096

__device__ __forceinline__ float nw_weight_exact(float cd) {
    float r  = __builtin_amdgcn_fractf(cd);
    float sn = __builtin_amdgcn_sinf(r);
    float cs = __builtin_amdgcn_cosf(r);
    float t  = (1.0f - cd) * (1.0f / 3.0f);
    float wt = fmaf(sn, 0.15915494309189535f, fmaf(cs, t, t + t));
    return fmaxf(wt, 0.0f);
}

__device__ __forceinline__ void split16(float x, _Float16& h, _Float16& l) {
    h = (_Float16)x;
    l = (_Float16)(x - (float)h);
}

// kfrag[key*2+g][j]: A-side slots; vfrag[(tile*2+set)*64+lane]: B-side V-frags
__global__ __launch_bounds__(256) void nw_prep(const float* __restrict__ k,
                                               const float* __restrict__ v,
                                               const float* __restrict__ kl,
                                               h8* __restrict__ kfrag,
                                               h8* __restrict__ vfrag,
                                               int M) {
    const int idx = blockIdx.x * 256 + threadIdx.x;
    const float iL = 1.0f / kl[0];
    const float ssL = iL * iL * (float)LUTN;
    if (idx < M) {
        const float x = k[(size_t)idx * 3 + 0];
        const float y = k[(size_t)idx * 3 + 1];
        const float z = k[(size_t)idx * 3 + 2];
        const float cx = -2.0f * ssL * x, cy = -2.0f * ssL * y, cz = -2.0f * ssL * z;
        const float k2 = ssL * fmaf(x, x, fmaf(y, y, z * z));
        _Float16 cxh, cxl, cyh, cyl, czh, czl, k2h, k2l;
        split16(cx, cxh, cxl); split16(cy, cyh, cyl);
        split16(cz, czh, czl); split16(k2, k2h, k2l);
        h8 lo = {cxh, cxh, cxl, cyh, cyh, cyl, czh, czh};
        h8 hi = {czl, k2h, k2l, (_Float16)1.0f, (_Float16)1.0f,
                 (_Float16)0.0f, (_Float16)0.0f, (_Float16)0.0f};
        kfrag[idx * 2 + 0] = lo;
        kfrag[idx * 2 + 1] = hi;
    }
    const int nv = (M / 32) * 128;   // tiles * 2 sets * 64 lanes
    if (idx < nv) {
        const int t = idx >> 7, r = idx & 127;
        const int set = r >> 6, l = r & 63;
        const int ch = l & 31, g = l >> 5;
        h8 o;
#pragma unroll
        for (int j = 0; j < 8; ++j) {
            const int key = t * 32 + set * 16 + ((j & 3) + 8 * (j >> 2) + 4 * g);
            const float val = (ch < 8) ? v[(size_t)key * 8 + ch]
                                       : (ch == 8 ? 1.0f : 0.0f);
            o[j] = (_Float16)val;
        }
        vfrag[(size_t)(t * 2 + set) * 64 + l] = o;
    }
}

__global__ __launch_bounds__(TPB) void nw_main(const float* __restrict__ q,
                                               const h8* __restrict__ kfrag,
                                               const h8* __restrict__ vfrag,
                                               const float* __restrict__ kl,
                                               float* __restrict__ part,
                                               int N) {
    __shared__ _Float16 lutw16[LUTN + 2];   // 8.2 KB fp16 LUT

    const int tid  = threadIdx.x;
    const int lane = tid & 63;
    const int wid  = tid >> 6;
    const int qg   = blockIdx.x;
    const int sb   = blockIdx.y;

    const float iL = 1.0f / kl[0];
    const float ssL = iL * iL * (float)LUTN;

    for (int e = tid; e <= LUTN; e += TPB)
        lutw16[e] = (_Float16)nw_weight_exact(
            __builtin_amdgcn_sqrtf((float)e * (1.0f / (float)LUTN)));
    __syncthreads();

    const int row = lane & 31;
    const int g   = lane >> 5;
    const int qi  = qg * QPB + wid * 32 + row;
    const float qx = q[qi * 3 + 0];
    const float qy = q[qi * 3 + 1];
    const float qz = q[qi * 3 + 2];
    const float q2 = ssL * fmaf(qx, qx, fmaf(qy, qy, qz * qz)) + 0.5f;

    _Float16 qxh, qxl, qyh, qyl, qzh, qzl, q2h, q2l;
    split16(qx, qxh, qxl); split16(qy, qyh, qyl);
    split16(qz, qzh, qzl); split16(q2, q2h, q2l);
    const _Float16 one = (_Float16)1.0f, zer = (_Float16)0.0f;
    // B-frag (constant across tiles): g=0 slots0..7, g=1 slots8..15
    h8 qf;
    qf[0] = g ? qzh : qxh;
    qf[1] = g ? one : qxl;
    qf[2] = g ? one : qxh;
    qf[3] = g ? q2h : qyh;
    qf[4] = g ? q2l : qyl;
    qf[5] = g ? zer : qyh;
    qf[6] = g ? zer : qzh;
    qf[7] = g ? zer : qzl;

    const h8* __restrict__ kfq = kfrag + (size_t)(sb * KSB) * 2;
    const h8* __restrict__ vfq = vfrag + (size_t)(sb * NTILE) * 128;

    f32x16 acc;
#pragma unroll
    for (int e = 0; e < 16; ++e) acc[e] = 0.0f;
    f32x16 zacc;
#pragma unroll
    for (int e = 0; e < 16; ++e) zacc[e] = 0.0f;

    for (int t = 0; t < NTILE; ++t) {
        const h8 ka  = kfq[(size_t)(t * 32 + row) * 2 + g];   // A1: per-lane 16B
        const h8 vfa = vfq[(size_t)(t * 2 + 0) * 64 + lane];
        const h8 vfb = vfq[(size_t)(t * 2 + 1) * 64 + lane];

        const f32x16 s = __builtin_amdgcn_mfma_f32_32x32x16_f16(ka, qf, zacc, 0, 0, 0);

        h8 afa, afb;
#pragma unroll
        for (int r = 0; r < 8; ++r) {
            float fx = fmaxf(fminf(s[r], (float)LUTN), 0.0f);   // v_med3
            afa[r] = lutw16[(unsigned)fx];                      // ds_read_u16
        }
#pragma unroll
        for (int r = 0; r < 8; ++r) {
            float fx = fmaxf(fminf(s[8 + r], (float)LUTN), 0.0f);
            afb[r] = lutw16[(unsigned)fx];
        }
        acc = __builtin_amdgcn_mfma_f32_32x32x16_f16(afa, vfa, acc, 0, 0, 0);
        acc = __builtin_amdgcn_mfma_f32_32x32x16_f16(afb, vfb, acc, 0, 0, 0);
    }

    // D: col=lane&31=channel, row=(reg&3)+8*(reg>>2)+4*g = local query
    const int ch = lane & 31;
    if (ch < 9) {
#pragma unroll
        for (int rq = 0; rq < 4; ++rq) {
            f32x4 o = {acc[4 * rq + 0], acc[4 * rq + 1], acc[4 * rq + 2], acc[4 * rq + 3]};
            const int gi = qg * QPB + wid * 32 + 8 * rq + 4 * g;
            *(f32x4*)(part + ((size_t)sb * 10 + ch) * N + gi) = o;
        }
    }
}

// out[i,c] = (sum_sb num) / (sum_sb den) + 1e-6
// grid: x = N/256 query-chunks, y = NCH channels; coalesced, ascending sb.
__global__ __launch_bounds__(256) void nw_reduce(const float* __restrict__ part,
                                                 float* __restrict__ out,
                                                 int N, int nsb) {
    const int i = blockIdx.x * 256 + threadIdx.x;
    const int c = blockIdx.y;
    if (i >= N) return;
    float s = 0.0f, d = 0.0f;
    for (int sb = 0; sb < nsb; ++sb) {
        const float* base = part + (size_t)sb * 10 * N;
        s += base[(size_t)c * N + i];
        d += base[8 * (size_t)N + i];
    }
    out[(size_t)i * NCH + c] = fmaf(s, 1.0f / d, 1e-6f);
}

// generic fallback: one thread per query over all keys (exact math)
__global__ __launch_bounds__(256) void nw_full(const float* __restrict__ q,
                                               const float* __restrict__ k,
                                               const float* __restrict__ v,
                                               const float* __restrict__ kl,
                                               float* __restrict__ out,
                                               int N, int M) {
    const int i = blockIdx.x * 256 + threadIdx.x;
    if (i >= N) return;
    const float qx = q[i * 3 + 0], qy = q[i * 3 + 1], qz = q[i * 3 + 2];
    const float invL = 1.0f / kl[0];
    float num[NCH];
#pragma unroll
    for (int c = 0; c < NCH; ++c) num[c] = 0.0f;
    float den = 0.0f;
    for (int j = 0; j < M; ++j) {
        float dx = qx - k[j * 3 + 0], dy = qy - k[j * 3 + 1], dz = qz - k[j * 3 + 2];
        float d2 = fmaf(dx, dx, fmaf(dy, dy, dz * dz));
        float wt = nw_weight_exact(__builtin_amdgcn_sqrtf(d2) * invL);
        den += wt;
#pragma unroll
        for (int c = 0; c < NCH; ++c) num[c] = fmaf(wt, v[j * NCH + c], num[c]);
    }
    const float rden = 1.0f / den;
#pragma unroll
    for (int c = 0; c < NCH; ++c) out[i * NCH + c] = fmaf(num[c], rden, 1e-6f);
}

extern "C" void kernel_launch(void* const* d_in, const int* in_sizes, int n_in,
                              void* d_out, int out_size, void* d_ws, size_t ws_size,
                              hipStream_t stream) {
    const float* q  = (const float*)d_in[0];
    const float* k  = (const float*)d_in[1];
    const float* v  = (const float*)d_in[2];
    const float* kl = (const float*)d_in[3];
    float* out = (float*)d_out;

    const int N = in_sizes[0] / 3;   // 8192 queries
    const int M = in_sizes[1] / 3;   // 8192 keys

    const int nsb = (M + KSB - 1) / KSB;
    const size_t part_sz  = (size_t)nsb * 10 * N * sizeof(float);
    const size_t kfrag_sz = (size_t)M * 2 * sizeof(h8);
    const size_t vfrag_sz = (size_t)(M / 32) * 128 * sizeof(h8);

    if ((N % QPB) == 0 && (M % KSB) == 0 && ws_size >= part_sz + kfrag_sz + vfrag_sz) {
        float* part  = (float*)d_ws;
        h8*    kfrag = (h8*)((char*)d_ws + part_sz);
        h8*    vfrag = (h8*)((char*)d_ws + part_sz + kfrag_sz);
        const int nprep = (M / 32) * 128;   // >= M
        nw_prep<<<(nprep + 255) / 256, 256, 0, stream>>>(k, v, kl, kfrag, vfrag, M);
        dim3 grid(N / QPB, nsb);
        nw_main<<<grid, TPB, 0, stream>>>(q, kfrag, vfrag, kl, part, N);
        dim3 rgrid((N + 255) / 256, NCH);
        nw_reduce<<<rgrid, 256, 0, stream>>>(part, out, N, nsb);
    } else {
        nw_full<<<(N + 255) / 256, 256, 0, stream>>>(q, k, v, kl, out, N, M);
    }
}

// Round 19
// 28.859 us; speedup vs baseline: 1.5028x; 1.1112x over previous
//
#include <hip/hip_runtime.h>

// NW kernel regression, double-MFMA (attention structure) — r18 skeleton
// (proven 32.1us) with two micro-cuts:
//  (1) clamp = fminf only: v_cvt_u32_f32 saturates negatives to 0 in HW,
//      so the fmaxf is redundant (-16 VALU/tile). Upper fminf kept (safe for
//      any L: LUT[4096]=0 = true w beyond the clamp).
//  (2) next-tile register prefetch of ka/vfa/vfb (TPB 512 kept — isolates the
//      prefetch from r16's failed TPB-256 bundle); hides per-tile L2 latency
//      under the gather phase.
//   MFMA1: fidx = ssL*(|q|^2+|k|^2-2q.k)+0.5 as rank-13 f16 hi/lo GEMM
//   VALU:  w = lut16[min(fidx, LUTN)]  (fp16 NN LUT, ds_read_u16)
//   MFMA2: [num|den] = W @ [V|1]  (ch8 = 1.0 denominator column)
// Conventions (proven r12/r14/r15/r17/r18):
//   A-frag 32x32x16: A[row=lane&31][slot=(lane>>5)*8+j]
//   B-frag:          B[slot=(lane>>5)*8+j][col=lane&31]
//   D:               col=lane&31, row=(reg&3)+8*(reg>>2)+4*(lane>>5)
//   vfrag key perm(g,j)=(j&3)+8*(j>>2)+4*g (+16 for set b), folded in prep.

typedef _Float16 h8 __attribute__((ext_vector_type(8)));
typedef float f32x16 __attribute__((ext_vector_type(16)));
typedef float f32x4 __attribute__((ext_vector_type(4)));

#define NCH 8
#define TPB 512        // 8 waves
#define QPB 256        // 8 waves x 32 query-rows
#define KSB 512        // keys per split = 16 tiles of 32
#define NTILE (KSB / 32)
#define LUTN 4096

__device__ __forceinline__ float nw_weight_exact(float cd) {
    float r  = __builtin_amdgcn_fractf(cd);
    float sn = __builtin_amdgcn_sinf(r);
    float cs = __builtin_amdgcn_cosf(r);
    float t  = (1.0f - cd) * (1.0f / 3.0f);
    float wt = fmaf(sn, 0.15915494309189535f, fmaf(cs, t, t + t));
    return fmaxf(wt, 0.0f);
}

__device__ __forceinline__ void split16(float x, _Float16& h, _Float16& l) {
    h = (_Float16)x;
    l = (_Float16)(x - (float)h);
}

// kfrag[key*2+g][j]: A-side slots; vfrag[(tile*2+set)*64+lane]: B-side V-frags
__global__ __launch_bounds__(256) void nw_prep(const float* __restrict__ k,
                                               const float* __restrict__ v,
                                               const float* __restrict__ kl,
                                               h8* __restrict__ kfrag,
                                               h8* __restrict__ vfrag,
                                               int M) {
    const int idx = blockIdx.x * 256 + threadIdx.x;
    const float iL = 1.0f / kl[0];
    const float ssL = iL * iL * (float)LUTN;
    if (idx < M) {
        const float x = k[(size_t)idx * 3 + 0];
        const float y = k[(size_t)idx * 3 + 1];
        const float z = k[(size_t)idx * 3 + 2];
        const float cx = -2.0f * ssL * x, cy = -2.0f * ssL * y, cz = -2.0f * ssL * z;
        const float k2 = ssL * fmaf(x, x, fmaf(y, y, z * z));
        _Float16 cxh, cxl, cyh, cyl, czh, czl, k2h, k2l;
        split16(cx, cxh, cxl); split16(cy, cyh, cyl);
        split16(cz, czh, czl); split16(k2, k2h, k2l);
        h8 lo = {cxh, cxh, cxl, cyh, cyh, cyl, czh, czh};
        h8 hi = {czl, k2h, k2l, (_Float16)1.0f, (_Float16)1.0f,
                 (_Float16)0.0f, (_Float16)0.0f, (_Float16)0.0f};
        kfrag[idx * 2 + 0] = lo;
        kfrag[idx * 2 + 1] = hi;
    }
    const int nv = (M / 32) * 128;   // tiles * 2 sets * 64 lanes
    if (idx < nv) {
        const int t = idx >> 7, r = idx & 127;
        const int set = r >> 6, l = r & 63;
        const int ch = l & 31, g = l >> 5;
        h8 o;
#pragma unroll
        for (int j = 0; j < 8; ++j) {
            const int key = t * 32 + set * 16 + ((j & 3) + 8 * (j >> 2) + 4 * g);
            const float val = (ch < 8) ? v[(size_t)key * 8 + ch]
                                       : (ch == 8 ? 1.0f : 0.0f);
            o[j] = (_Float16)val;
        }
        vfrag[(size_t)(t * 2 + set) * 64 + l] = o;
    }
}

__global__ __launch_bounds__(TPB) void nw_main(const float* __restrict__ q,
                                               const h8* __restrict__ kfrag,
                                               const h8* __restrict__ vfrag,
                                               const float* __restrict__ kl,
                                               float* __restrict__ part,
                                               int N) {
    __shared__ _Float16 lutw16[LUTN + 2];   // 8.2 KB fp16 LUT

    const int tid  = threadIdx.x;
    const int lane = tid & 63;
    const int wid  = tid >> 6;
    const int qg   = blockIdx.x;
    const int sb   = blockIdx.y;

    const float iL = 1.0f / kl[0];
    const float ssL = iL * iL * (float)LUTN;

    for (int e = tid; e <= LUTN; e += TPB)
        lutw16[e] = (_Float16)nw_weight_exact(
            __builtin_amdgcn_sqrtf((float)e * (1.0f / (float)LUTN)));
    __syncthreads();

    const int row = lane & 31;
    const int g   = lane >> 5;
    const int qi  = qg * QPB + wid * 32 + row;
    const float qx = q[qi * 3 + 0];
    const float qy = q[qi * 3 + 1];
    const float qz = q[qi * 3 + 2];
    const float q2 = ssL * fmaf(qx, qx, fmaf(qy, qy, qz * qz)) + 0.5f;

    _Float16 qxh, qxl, qyh, qyl, qzh, qzl, q2h, q2l;
    split16(qx, qxh, qxl); split16(qy, qyh, qyl);
    split16(qz, qzh, qzl); split16(q2, q2h, q2l);
    const _Float16 one = (_Float16)1.0f, zer = (_Float16)0.0f;
    // B-frag (constant across tiles): g=0 slots0..7, g=1 slots8..15
    h8 qf;
    qf[0] = g ? qzh : qxh;
    qf[1] = g ? one : qxl;
    qf[2] = g ? one : qxh;
    qf[3] = g ? q2h : qyh;
    qf[4] = g ? q2l : qyl;
    qf[5] = g ? zer : qyh;
    qf[6] = g ? zer : qzh;
    qf[7] = g ? zer : qzl;

    const h8* __restrict__ kfq = kfrag + (size_t)(sb * KSB) * 2;
    const h8* __restrict__ vfq = vfrag + (size_t)(sb * NTILE) * 128;

    f32x16 acc;
#pragma unroll
    for (int e = 0; e < 16; ++e) acc[e] = 0.0f;
    f32x16 zacc;
#pragma unroll
    for (int e = 0; e < 16; ++e) zacc[e] = 0.0f;

    // tile-0 operands
    h8 ka  = kfq[(size_t)row * 2 + g];
    h8 vfa = vfq[lane];
    h8 vfb = vfq[64 + lane];

    for (int t = 0; t < NTILE; ++t) {
        const int tn = (t + 1 < NTILE) ? t + 1 : t;
        const h8 ka_n  = kfq[(size_t)(tn * 32 + row) * 2 + g];
        const h8 vfa_n = vfq[(size_t)(tn * 2 + 0) * 64 + lane];
        const h8 vfb_n = vfq[(size_t)(tn * 2 + 1) * 64 + lane];

        const f32x16 s = __builtin_amdgcn_mfma_f32_32x32x16_f16(ka, qf, zacc, 0, 0, 0);

        h8 afa, afb;
#pragma unroll
        for (int r = 0; r < 8; ++r) {
            const float fx = fminf(s[r], (float)LUTN);      // lower clamp: HW cvt sat
            afa[r] = lutw16[(unsigned)fx];                  // ds_read_u16
        }
#pragma unroll
        for (int r = 0; r < 8; ++r) {
            const float fx = fminf(s[8 + r], (float)LUTN);
            afb[r] = lutw16[(unsigned)fx];
        }
        acc = __builtin_amdgcn_mfma_f32_32x32x16_f16(afa, vfa, acc, 0, 0, 0);
        acc = __builtin_amdgcn_mfma_f32_32x32x16_f16(afb, vfb, acc, 0, 0, 0);

        ka = ka_n; vfa = vfa_n; vfb = vfb_n;
    }

    // D: col=lane&31=channel, row=(reg&3)+8*(reg>>2)+4*g = local query
    const int ch = lane & 31;
    if (ch < 9) {
#pragma unroll
        for (int rq = 0; rq < 4; ++rq) {
            f32x4 o = {acc[4 * rq + 0], acc[4 * rq + 1], acc[4 * rq + 2], acc[4 * rq + 3]};
            const int gi = qg * QPB + wid * 32 + 8 * rq + 4 * g;
            *(f32x4*)(part + ((size_t)sb * 10 + ch) * N + gi) = o;
        }
    }
}

// out[i,c] = (sum_sb num) / (sum_sb den) + 1e-6
// grid: x = N/256 query-chunks, y = NCH channels; coalesced, ascending sb.
__global__ __launch_bounds__(256) void nw_reduce(const float* __restrict__ part,
                                                 float* __restrict__ out,
                                                 int N, int nsb) {
    const int i = blockIdx.x * 256 + threadIdx.x;
    const int c = blockIdx.y;
    if (i >= N) return;
    float s = 0.0f, d = 0.0f;
    for (int sb = 0; sb < nsb; ++sb) {
        const float* base = part + (size_t)sb * 10 * N;
        s += base[(size_t)c * N + i];
        d += base[8 * (size_t)N + i];
    }
    out[(size_t)i * NCH + c] = fmaf(s, 1.0f / d, 1e-6f);
}

// generic fallback: one thread per query over all keys (exact math)
__global__ __launch_bounds__(256) void nw_full(const float* __restrict__ q,
                                               const float* __restrict__ k,
                                               const float* __restrict__ v,
                                               const float* __restrict__ kl,
                                               float* __restrict__ out,
                                               int N, int M) {
    const int i = blockIdx.x * 256 + threadIdx.x;
    if (i >= N) return;
    const float qx = q[i * 3 + 0], qy = q[i * 3 + 1], qz = q[i * 3 + 2];
    const float invL = 1.0f / kl[0];
    float num[NCH];
#pragma unroll
    for (int c = 0; c < NCH; ++c) num[c] = 0.0f;
    float den = 0.0f;
    for (int j = 0; j < M; ++j) {
        float dx = qx - k[j * 3 + 0], dy = qy - k[j * 3 + 1], dz = qz - k[j * 3 + 2];
        float d2 = fmaf(dx, dx, fmaf(dy, dy, dz * dz));
        float wt = nw_weight_exact(__builtin_amdgcn_sqrtf(d2) * invL);
        den += wt;
#pragma unroll
        for (int c = 0; c < NCH; ++c) num[c] = fmaf(wt, v[j * NCH + c], num[c]);
    }
    const float rden = 1.0f / den;
#pragma unroll
    for (int c = 0; c < NCH; ++c) out[i * NCH + c] = fmaf(num[c], rden, 1e-6f);
}

extern "C" void kernel_launch(void* const* d_in, const int* in_sizes, int n_in,
                              void* d_out, int out_size, void* d_ws, size_t ws_size,
                              hipStream_t stream) {
    const float* q  = (const float*)d_in[0];
    const float* k  = (const float*)d_in[1];
    const float* v  = (const float*)d_in[2];
    const float* kl = (const float*)d_in[3];
    float* out = (float*)d_out;

    const int N = in_sizes[0] / 3;   // 8192 queries
    const int M = in_sizes[1] / 3;   // 8192 keys

    const int nsb = (M + KSB - 1) / KSB;
    const size_t part_sz  = (size_t)nsb * 10 * N * sizeof(float);
    const size_t kfrag_sz = (size_t)M * 2 * sizeof(h8);
    const size_t vfrag_sz = (size_t)(M / 32) * 128 * sizeof(h8);

    if ((N % QPB) == 0 && (M % KSB) == 0 && ws_size >= part_sz + kfrag_sz + vfrag_sz) {
        float* part  = (float*)d_ws;
        h8*    kfrag = (h8*)((char*)d_ws + part_sz);
        h8*    vfrag = (h8*)((char*)d_ws + part_sz + kfrag_sz);
        const int nprep = (M / 32) * 128;   // >= M
        nw_prep<<<(nprep + 255) / 256, 256, 0, stream>>>(k, v, kl, kfrag, vfrag, M);
        dim3 grid(N / QPB, nsb);
        nw_main<<<grid, TPB, 0, stream>>>(q, kfrag, vfrag, kl, part, N);
        dim3 rgrid((N + 255) / 256, NCH);
        nw_reduce<<<rgrid, 256, 0, stream>>>(part, out, N, nsb);
    } else {
        nw_full<<<(N + 255) / 256, 256, 0, stream>>>(q, k, v, kl, out, N, M);
    }
}